// Round 16
// baseline (178.627 us; speedup 1.0000x reference)
//
#include <hip/hip_runtime.h>

typedef unsigned short u16;
typedef __attribute__((ext_vector_type(8))) short short8;
typedef __attribute__((ext_vector_type(4))) float floatx4;

#define D_MODEL 1024
#define NHEADS 16
#define HD 64
#define BATCH 2
#define SEQ 2048
#define MROWS (BATCH * SEQ)  // 4096

static __device__ __forceinline__ u16 f2bf(float f) {
  unsigned int u = __float_as_uint(f);
  u += 0x7fffu + ((u >> 16) & 1u);  // round-to-nearest-even
  return (u16)(u >> 16);
}

static __device__ __forceinline__ void glds16(const u16* g, u16* l) {
  __builtin_amdgcn_global_load_lds(
      (const __attribute__((address_space(1))) void*)g,
      (__attribute__((address_space(3))) void*)l, 16, 0, 0);
}

// ---------------- fused fp32 -> bf16 convert for all 5 inputs ----------------
__global__ void cvt_all(const float* __restrict__ x, const float* __restrict__ wq,
                        const float* __restrict__ wk, const float* __restrict__ wv,
                        const float* __restrict__ wo, u16* __restrict__ xb,
                        u16* __restrict__ wqkvb, u16* __restrict__ wob) {
  const int i = blockIdx.x * 256 + threadIdx.x;
  const int chunk = i >> 18;
  const float* src;
  u16* dst;
  int loc;
  switch (chunk) {
    case 0: case 1: case 2: case 3: src = x;  dst = xb;              loc = i;              break;
    case 4:                          src = wq; dst = wqkvb;           loc = i - (4 << 18); break;
    case 5:                          src = wk; dst = wqkvb + 1048576; loc = i - (5 << 18); break;
    case 6:                          src = wv; dst = wqkvb + 2097152; loc = i - (6 << 18); break;
    default:                         src = wo; dst = wob;             loc = i - (7 << 18); break;
  }
  const float4 v = ((const float4*)src)[loc];
  ushort4 o;
  o.x = f2bf(v.x); o.y = f2bf(v.y); o.z = f2bf(v.z); o.w = f2bf(v.w);
  ((ushort4*)dst)[loc] = o;
}

// ---------------- bf16 MFMA NT-GEMM 128x128, BK=64, fused RoPE QKV scatter ----------------
// v2.1 epilogue: Q/K stores via padded LDS transpose tile (128x132) then
// coalesced uint4 global stores. FIX vs v2: readback needs 8 passes (2048
// 16B stores for the 32KB tile), not 4 -- rows 64..127 were dropped.
__global__ __launch_bounds__(256) void gemm_qkv(
    const u16* __restrict__ A, const u16* __restrict__ B,
    u16* __restrict__ qb, u16* __restrict__ kb, u16* __restrict__ vb, int K) {
  __shared__ u16 smem[128 * 132];      // staging (2x128x32 As + Bs) or transpose tile
  u16* As = smem;                      // [2][128*32]
  u16* Bs = smem + 8192;               // [2][128*32]
  const int t = threadIdx.x;
  const int lane = t & 63;
  const int wv = t >> 6;
  const int wr = wv >> 1, wc = wv & 1;
  const int m0 = blockIdx.y * 128, n0 = blockIdx.x * 128;
  const int qd = lane >> 4, lr = lane & 15;
  const int arow = lane >> 2;
  const int acol = (lane & 3) * 8;

  floatx4 acc[4][4];
#pragma unroll
  for (int i = 0; i < 4; ++i)
#pragma unroll
    for (int j = 0; j < 4; ++j) acc[i][j] = (floatx4){0.f, 0.f, 0.f, 0.f};

  for (int kt = 0; kt < K; kt += 64) {
    __syncthreads();
#pragma unroll
    for (int kh = 0; kh < 2; ++kh) {
#pragma unroll
      for (int i = 0; i < 2; ++i) {
        const int seg = wv * 2 + i;
        glds16(&A[(size_t)(m0 + seg * 16 + arow) * K + kt + kh * 32 + acol], &As[kh * 4096 + seg * 512]);
        glds16(&B[(size_t)(n0 + seg * 16 + arow) * K + kt + kh * 32 + acol], &Bs[kh * 4096 + seg * 512]);
      }
    }
    __syncthreads();

#pragma unroll
    for (int kh = 0; kh < 2; ++kh) {
      short8 af[4], bfr[4];
#pragma unroll
      for (int i = 0; i < 4; ++i)
        af[i] = *(const short8*)&As[kh * 4096 + (wr * 64 + i * 16 + lr) * 32 + qd * 8];
#pragma unroll
      for (int j = 0; j < 4; ++j)
        bfr[j] = *(const short8*)&Bs[kh * 4096 + (wc * 64 + j * 16 + lr) * 32 + qd * 8];
#pragma unroll
      for (int i = 0; i < 4; ++i)
#pragma unroll
        for (int j = 0; j < 4; ++j)
          acc[i][j] = __builtin_amdgcn_mfma_f32_16x16x32_bf16(af[i], bfr[j], acc[i][j], 0, 0, 0);
    }
  }

  const int tn = n0 >> 10;  // block-uniform tensor id
  if (tn == 2) {            // V: transposed store [B,H,HD,S] (already vectorized)
#pragma unroll
    for (int i = 0; i < 4; ++i) {
      const int mb = m0 + wr * 64 + i * 16 + qd * 4;
      const int b = mb >> 11, s = mb & 2047;
#pragma unroll
      for (int j = 0; j < 4; ++j) {
        const int nn = (n0 + wc * 64 + j * 16 + lr) & 1023;
        const int h = nn >> 6, d = nn & 63;
        ushort4 o;
        o.x = f2bf(acc[i][j][0]); o.y = f2bf(acc[i][j][1]);
        o.z = f2bf(acc[i][j][2]); o.w = f2bf(acc[i][j][3]);
        *(ushort4*)&vb[((size_t)(b * NHEADS + h) * HD + d) * SEQ + s] = o;
      }
    }
  } else {                  // Q or K: RoPE in-register, LDS transpose, coalesced store
    u16* dst = (tn == 0) ? qb : kb;
    const float qs = (tn == 0) ? 0.18033688011112042f : 1.0f;
    const float inv0 = __builtin_exp2f(-(float)lr * 0.4152410118609203f);
    const float inv1 = __builtin_exp2f(-(float)(lr + 16) * 0.4152410118609203f);
    __syncthreads();  // all waves done reading As/Bs; smem becomes transpose tile
#pragma unroll
    for (int i = 0; i < 4; ++i) {
      const int rowb = wr * 64 + i * 16 + qd * 4;  // m-local
      const int mb = m0 + rowb;
#pragma unroll
      for (int r = 0; r < 4; ++r) {
        const int sq = (mb + r) & 2047;
        float s0, c0, s1, c1;
        __sincosf((float)sq * inv0, &s0, &c0);
        __sincosf((float)sq * inv1, &s1, &c1);
#pragma unroll
        for (int j = 0; j < 4; ++j) {
          const float v = acc[i][j][r];
          const float pv = acc[i][j ^ 2][r];  // rope partner d^32
          const float cc = (j & 1) ? c1 : c0;
          const float ss = (j & 1) ? s1 : s0;
          const float res = (v * cc + ((j < 2) ? -pv : pv) * ss) * qs;
          smem[(rowb + r) * 132 + wc * 64 + j * 16 + lr] = f2bf(res);
        }
      }
    }
    __syncthreads();
    // readback: 8 passes x 256 threads -> 2048 uint4 stores covering all 128 rows
#pragma unroll
    for (int p = 0; p < 8; ++p) {
      const int idx = p * 256 + t;          // 0..2047
      const int row = idx >> 4, col = (idx & 15) * 8;
      const uint4 vv = *(const uint4*)&smem[row * 132 + col];
      const int m = m0 + row;
      const int b = m >> 11, sq = m & 2047;
      const int nn = (n0 + col) & 1023;
      const int h = nn >> 6, d = nn & 63;
      *(uint4*)&dst[((size_t)(b * NHEADS + h) * SEQ + sq) * HD + d] = vv;
    }
  }
}

// ---------------- bf16 MFMA NT-GEMM 64x64, BK=64 (out-proj): fp32 store ----------------
__global__ __launch_bounds__(256) void gemm_out(
    const u16* __restrict__ A, const u16* __restrict__ B, float* __restrict__ fo,
    int N, int K) {
  __shared__ u16 As[2][64 * 32];
  __shared__ u16 Bs[2][64 * 32];
  const int t = threadIdx.x;
  const int lane = t & 63, wv = t >> 6;
  const int m0 = blockIdx.y * 64, n0 = blockIdx.x * 64;
  const int qd = lane >> 4, lr = lane & 15;
  const int arow = lane >> 2;
  const int acol = (lane & 3) * 8;

  floatx4 acc[4];
#pragma unroll
  for (int j = 0; j < 4; ++j) acc[j] = (floatx4){0.f, 0.f, 0.f, 0.f};

  for (int kt = 0; kt < K; kt += 64) {
    __syncthreads();
#pragma unroll
    for (int kh = 0; kh < 2; ++kh) {
      glds16(&A[(size_t)(m0 + wv * 16 + arow) * K + kt + kh * 32 + acol], &As[kh][wv * 512]);
      glds16(&B[(size_t)(n0 + wv * 16 + arow) * K + kt + kh * 32 + acol], &Bs[kh][wv * 512]);
    }
    __syncthreads();

#pragma unroll
    for (int kh = 0; kh < 2; ++kh) {
      const short8 af = *(const short8*)&As[kh][(wv * 16 + lr) * 32 + qd * 8];
#pragma unroll
      for (int j = 0; j < 4; ++j) {
        const short8 bfr = *(const short8*)&Bs[kh][(j * 16 + lr) * 32 + qd * 8];
        acc[j] = __builtin_amdgcn_mfma_f32_16x16x32_bf16(af, bfr, acc[j], 0, 0, 0);
      }
    }
  }
#pragma unroll
  for (int j = 0; j < 4; ++j)
#pragma unroll
    for (int r = 0; r < 4; ++r)
      fo[(size_t)(m0 + wv * 16 + qd * 4 + r) * N + n0 + j * 16 + lr] = acc[j][r];
}

// ---------------- causal flash attention v6 (unchanged from round 14) ----------------
__global__ __launch_bounds__(256, 2) void flash_mfma(
    const u16* __restrict__ Q, const u16* __restrict__ Kg,
    const u16* __restrict__ Vg, u16* __restrict__ O) {
  __shared__ u16 Ks[2][2][2][64 * 32];  // [buf][key64-sub][d-half][key*32 + d]
  __shared__ u16 Vs[2][2][2][64 * 32];  // [buf][key64-sub][key32-half][d*32 + key]
  __shared__ u16 Ps[4][16][72];         // [wave][q][64 keys + pad], reused per subtile
  const int t = threadIdx.x;
  const int lane = t & 63, wv = t >> 6;
  const int lr = lane & 15, qd = lane >> 4;
  const int bh = blockIdx.x;
  const int y = (int)blockIdx.y;
  const int c = (y < 8) ? (15 - y) : (y - 8);  // CU-balanced pairing
  const int nst2 = c + 1;                      // 128-key steps
  const int q0w = c * 128 + wv * 32;
  const size_t baseQK = (size_t)bh * SEQ * HD;
  const size_t baseV = (size_t)bh * HD * SEQ;
  const int b = bh >> 4, h = bh & 15;
  const int srow = lane >> 2;
  const int scol = (lane & 3) * 8;

  auto stage = [&](int buf, int k0) {
    if (wv < 2) {
      const int sub = wv;
#pragma unroll
      for (int hh = 0; hh < 2; ++hh)
#pragma unroll
        for (int seg = 0; seg < 4; ++seg)
          glds16(&Kg[baseQK + (size_t)(k0 + sub * 64 + seg * 16 + srow) * HD + hh * 32 + scol],
                 &Ks[buf][sub][hh][seg * 512]);
    } else {
      const int sub = wv - 2;
#pragma unroll
      for (int hh = 0; hh < 2; ++hh)
#pragma unroll
        for (int seg = 0; seg < 4; ++seg)
          glds16(&Vg[baseV + (size_t)(seg * 16 + srow) * SEQ + k0 + sub * 64 + hh * 32 + scol],
                 &Vs[buf][sub][hh][seg * 512]);
    }
  };

  short8 qf[2][2];
#pragma unroll
  for (int i = 0; i < 2; ++i)
#pragma unroll
    for (int s = 0; s < 2; ++s)
      qf[i][s] = *(const short8*)&Q[baseQK + (size_t)(q0w + i * 16 + lr) * HD + s * 32 + qd * 8];

  float l_i[2] = {0.f, 0.f};
  floatx4 oacc[2][4];
#pragma unroll
  for (int i = 0; i < 2; ++i)
#pragma unroll
    for (int dj = 0; dj < 4; ++dj) oacc[i][dj] = (floatx4){0.f, 0.f, 0.f, 0.f};

  stage(0, 0);

  for (int kt2 = 0; kt2 < nst2; ++kt2) {
    __syncthreads();  // vmcnt drain: buf[kt2&1] ready; prev readers done
    if (kt2 + 1 < nst2) stage((kt2 + 1) & 1, (kt2 + 1) * 128);
    const int buf = kt2 & 1;

#pragma unroll
    for (int sub = 0; sub < 2; ++sub) {
      const int k0 = kt2 * 128 + sub * 64;
      if (k0 > q0w + 31) continue;  // wave fully masked (wave-uniform, no barrier inside)

      short8 kf[2][4], vf[2][4];
#pragma unroll
      for (int s = 0; s < 2; ++s)
#pragma unroll
        for (int jj = 0; jj < 4; ++jj)
          kf[s][jj] = *(const short8*)&Ks[buf][sub][s][(jj * 16 + lr) * 32 + qd * 8];
#pragma unroll
      for (int s = 0; s < 2; ++s)
#pragma unroll
        for (int dj = 0; dj < 4; ++dj)
          vf[s][dj] = *(const short8*)&Vs[buf][sub][s][(dj * 16 + lr) * 32 + qd * 8];

      floatx4 sv[2][4];
#pragma unroll
      for (int i = 0; i < 2; ++i)
#pragma unroll
        for (int jj = 0; jj < 4; ++jj) sv[i][jj] = (floatx4){0.f, 0.f, 0.f, 0.f};
#pragma unroll
      for (int s = 0; s < 2; ++s)
#pragma unroll
        for (int jj = 0; jj < 4; ++jj) {
          sv[1][jj] = __builtin_amdgcn_mfma_f32_16x16x32_bf16(kf[s][jj], qf[1][s], sv[1][jj], 0, 0, 0);
          sv[0][jj] = __builtin_amdgcn_mfma_f32_16x16x32_bf16(kf[s][jj], qf[0][s], sv[0][jj], 0, 0, 0);
        }

#pragma unroll
      for (int i = 0; i < 2; ++i) {
        const int dq = (q0w + i * 16) - k0;  // multiple of 16, >= 0
        if (dq < 63) {                       // diagonal overlap: mask key > q
#pragma unroll
          for (int jj = 0; jj < 4; ++jj)
#pragma unroll
            for (int r = 0; r < 4; ++r)
              if (jj * 16 + qd * 4 + r > dq + lr) sv[i][jj][r] = -1e30f;
        }
        float rs = 0.f;
#pragma unroll
        for (int jj = 0; jj < 4; ++jj) {
          const float p0 = __builtin_exp2f(sv[i][jj][0]);
          const float p1 = __builtin_exp2f(sv[i][jj][1]);
          const float p2 = __builtin_exp2f(sv[i][jj][2]);
          const float p3 = __builtin_exp2f(sv[i][jj][3]);
          rs += (p0 + p1) + (p2 + p3);
          uint2 pk;  // truncating bf16x2 packs, keys ascending
          pk.x = __builtin_amdgcn_perm(__float_as_uint(p1), __float_as_uint(p0), 0x07060302);
          pk.y = __builtin_amdgcn_perm(__float_as_uint(p3), __float_as_uint(p2), 0x07060302);
          *(uint2*)&Ps[wv][lr][jj * 16 + qd * 4] = pk;
        }
        l_i[i] += rs;

        const short8 pf0 = *(const short8*)&Ps[wv][lr][qd * 8];
        const short8 pf1 = *(const short8*)&Ps[wv][lr][32 + qd * 8];
#pragma unroll
        for (int dj = 0; dj < 4; ++dj)
          oacc[i][dj] = __builtin_amdgcn_mfma_f32_16x16x32_bf16(pf0, vf[0][dj], oacc[i][dj], 0, 0, 0);
#pragma unroll
        for (int dj = 0; dj < 4; ++dj)
          oacc[i][dj] = __builtin_amdgcn_mfma_f32_16x16x32_bf16(pf1, vf[1][dj], oacc[i][dj], 0, 0, 0);
      }
    }
  }

#pragma unroll
  for (int i = 0; i < 2; ++i) {
    float lf = l_i[i];
    lf += __shfl_xor(lf, 16, 64);
    lf += __shfl_xor(lf, 32, 64);
#pragma unroll
    for (int r = 0; r < 4; ++r) {
      const float linv = 1.f / __shfl(lf, qd * 4 + r, 64);
      const int q = q0w + i * 16 + qd * 4 + r;
#pragma unroll
      for (int dj = 0; dj < 4; ++dj)
        O[(size_t)(b * SEQ + q) * D_MODEL + h * HD + dj * 16 + lr] = f2bf(oacc[i][dj][r] * linv);
    }
  }
}

extern "C" void kernel_launch(void* const* d_in, const int* in_sizes, int n_in,
                              void* d_out, int out_size, void* d_ws, size_t ws_size,
                              hipStream_t stream) {
  const float* x  = (const float*)d_in[0];
  const float* Wq = (const float*)d_in[1];
  const float* Wk = (const float*)d_in[2];
  const float* Wv = (const float*)d_in[3];
  const float* Wo = (const float*)d_in[4];
  float* out = (float*)d_out;

  u16* xb = (u16*)d_ws;            // x bf16        [4096,1024]
  u16* wqkv = xb + 4194304;        // Wq|Wk|Wv bf16 [3072,1024]
  u16* wo = wqkv + 3145728;        // Wo bf16       [1024,1024]
  u16* qb = wo + 1048576;          // Q bf16 [B,H,S,HD] (rope'd, *0.125*log2e)
  u16* kb = qb + 4194304;          // K bf16 [B,H,S,HD] (rope'd)
  u16* vb = kb + 4194304;          // V bf16 [B,H,HD,S] (transposed)
  u16* ow = vb + 4194304;          // O bf16 [B,S,D]

  cvt_all<<<8192, 256, 0, stream>>>(x, Wq, Wk, Wv, Wo, xb, wqkv, wo);
  gemm_qkv<<<dim3(24, 32), 256, 0, stream>>>(xb, wqkv, qb, kb, vb, 1024);
  flash_mfma<<<dim3(32, 16), 256, 0, stream>>>(qb, kb, vb, ow);
  gemm_out<<<dim3(16, 64), 256, 0, stream>>>(ow, wo, out, 1024, 1024);
}